// Round 19
// baseline (103.257 us; speedup 1.0000x reference)
//
#include <hip/hip_runtime.h>

#define B_  32
#define CL_ 1024
#define QL_ 512
#define D_  256

typedef _Float16 f16;
typedef __attribute__((ext_vector_type(2))) _Float16 f16x2;
typedef __attribute__((ext_vector_type(4))) _Float16 f16x4;
typedef __attribute__((ext_vector_type(8))) _Float16 f16x8;
typedef __attribute__((ext_vector_type(4))) float    f32x4;

// ------- K0: q -> fragment-ordered qF/qTF + sqv --------------------------
__global__ __launch_bounds__(256) void k0_prep(const float* __restrict__ q,
                                               const float* __restrict__ w_q,
                                               f16* __restrict__ qF,
                                               f16* __restrict__ qTF,
                                               float* __restrict__ sqv) {
  __shared__ f16 q_l[64][258];
  int b = blockIdx.y, J = blockIdx.x, j0 = J * 64, tid = threadIdx.x;
  int r = tid >> 2, seg = tid & 3;
  const float* qrow = q + ((size_t)(b * QL_ + j0 + r)) * D_ + seg * 64;
  float dot = 0.f;
  #pragma unroll
  for (int u = 0; u < 16; ++u) {
    f32x4 v  = *(const f32x4*)(qrow + 4 * u);
    f32x4 wv = *(const f32x4*)(w_q + seg * 64 + 4 * u);
    f16x4 h;
    h[0] = (f16)v[0]; h[1] = (f16)v[1]; h[2] = (f16)v[2]; h[3] = (f16)v[3];
    *(f16x4*)(&q_l[r][seg * 64 + 4 * u]) = h;
    dot += v[0]*wv[0] + v[1]*wv[1] + v[2]*wv[2] + v[3]*wv[3];
  }
  dot += __shfl_xor(dot, 1, 64);
  dot += __shfl_xor(dot, 2, 64);
  if (seg == 0) sqv[b * QL_ + j0 + r] = dot;
  __syncthreads();

  const int ww = tid >> 6, l = tid & 63, g = l >> 4, l15 = l & 15;
  f16* qFb = qF + ((size_t)(b * 8 + J)) * 16384;
  #pragma unroll
  for (int t = 0; t < 8; ++t) {
    int task = ww * 8 + t;            // (dk,fj)
    int dk = task >> 2, fj = task & 3;
    f16x8 v = *(const f16x8*)(&q_l[16 * fj + l15][dk * 32 + 8 * g]);
    *(f16x8*)(qFb + ((size_t)task * 64 + l) * 8) = v;
  }
  #pragma unroll
  for (int t = 0; t < 8; ++t) {
    int task = ww * 8 + t;            // (W,jtl,fd)
    int W = task >> 2, jtl = (task >> 1) & 1, fd = task & 1;
    f16x8 v;
    #pragma unroll
    for (int e = 0; e < 8; ++e)
      v[e] = q_l[32 * jtl + 8 * g + e][32 * W + 16 * fd + l15];
    *(f16x8*)(qTF + ((((size_t)(b * 8 + W) * 16 + (2 * J + jtl)) * 2 + fd) * 64 + l) * 8) = v;
  }
}

// ------- K1, BM=32, 256 thr (4 waves), 4 blocks/CU -----------------------
// Phase A: wave w owns j in [128w,128w+128) (J=2w,2w+1). Merged 1-pass
// softmax (wave-local max+sumexp, single cross-wave combine, per-wave
// factor folded into P scale). Phase C: wave w owns d in [64w,64w+64).
// LDS 38656 B -> 4 blocks/CU; lb(256,4) caps VGPR at 128.
__global__ __launch_bounds__(256, 4) void k1_fused(
    const float* __restrict__ c, const f16* __restrict__ qF,
    const f16* __restrict__ qTF, const float* __restrict__ sqv,
    const float* __restrict__ w_c, const float* __restrict__ w_cq,
    f16* __restrict__ c2qh, float* __restrict__ mrow)
{
  __shared__ alignas(16) char smem[38656];
  f16 (*cw_t)[264]  = (f16 (*)[264])(smem);            // 16896 (phase A)
  char* P_b         = smem;                            // 32768 swz (B/C)
  f16 (*c2q_l)[264] = (f16 (*)[264])(smem);            // 16896 alias (tail)
  float* sqv_l = (float*)(smem + 32768);               // 2048
  float* wcq_l = (float*)(smem + 34816);               // 1024
  float* wc_l  = (float*)(smem + 35840);               // 1024
  float* scv_l = (float*)(smem + 36864);               // 128
  float (*red_m)[32] = (float (*)[32])(smem + 36992);  // 512
  float (*red_s)[32] = (float (*)[32])(smem + 37504);  // 512
  float (*fac)[32]   = (float (*)[32])(smem + 38016);  // 512
  // total 38528 (+pad)

  const int tid = threadIdx.x;
  const int w = tid >> 6, l = tid & 63, g = l >> 4, l15 = l & 15;
  const int lin = blockIdx.x, xcd = lin & 7, slot = lin >> 3;   // 0..127
  const int b  = xcd * 4 + (slot >> 5);
  const int i0 = (slot & 31) * 32;

  wcq_l[tid] = w_cq[tid]; wc_l[tid] = w_c[tid];
  sqv_l[tid] = sqv[b * QL_ + tid];
  sqv_l[tid + 256] = sqv[b * QL_ + tid + 256];
  __syncthreads();

  // ---- stage cw_t = f16(c * w_cq) (32 rows); scv = c . w_c -------------
  {
    int row = tid >> 3, seg = tid & 7;               // 8 thr/row, 32 f32 each
    const float* crow = c + (size_t)(b * CL_ + i0 + row) * D_ + seg * 32;
    float dot = 0.f;
    #pragma unroll
    for (int u = 0; u < 8; ++u) {
      f32x4 v  = *(const f32x4*)(crow + 4 * u);
      f32x4 wv = *(const f32x4*)(wcq_l + seg * 32 + 4 * u);
      f32x4 w2 = *(const f32x4*)(wc_l  + seg * 32 + 4 * u);
      f16x4 h;
      h[0] = (f16)(v[0]*wv[0]); h[1] = (f16)(v[1]*wv[1]);
      h[2] = (f16)(v[2]*wv[2]); h[3] = (f16)(v[3]*wv[3]);
      *(f16x4*)(&cw_t[row][seg * 32 + 4 * u]) = h;
      dot += v[0]*w2[0] + v[1]*w2[1] + v[2]*w2[2] + v[3]*w2[3];
    }
    dot += __shfl_xor(dot, 1, 64); dot += __shfl_xor(dot, 2, 64);
    dot += __shfl_xor(dot, 4, 64);
    if (seg == 0) scv_l[row] = dot;
  }
  __syncthreads();

  // ---- Phase A: wave w owns j in [128w,128w+128); fragment streams -----
  f32x4 acc[2][2][4];   // [fi][jj][fj], all static indices
  #pragma unroll
  for (int fi = 0; fi < 2; ++fi)
    #pragma unroll
    for (int jj = 0; jj < 2; ++jj)
      #pragma unroll
      for (int fj = 0; fj < 4; ++fj)
        acc[fi][jj][fj] = (f32x4){0.f,0.f,0.f,0.f};

  const f16* qFb0 = qF + ((size_t)(b * 8 + 2 * w)) * 16384;
  const f16* qFb1 = qFb0 + 16384;
  #pragma unroll
  for (int dk = 0; dk < 8; ++dk) {
    f16x8 av0 = *(const f16x8*)(&cw_t[l15     ][dk * 32 + 8 * g]);
    f16x8 av1 = *(const f16x8*)(&cw_t[16 + l15][dk * 32 + 8 * g]);
    #pragma unroll
    for (int fj = 0; fj < 4; ++fj) {
      f16x8 bf0 = *(const f16x8*)(qFb0 + (((size_t)dk * 4 + fj) * 64 + l) * 8);
      f16x8 bf1 = *(const f16x8*)(qFb1 + (((size_t)dk * 4 + fj) * 64 + l) * 8);
      acc[0][0][fj] = __builtin_amdgcn_mfma_f32_16x16x32_f16(av0, bf0, acc[0][0][fj], 0, 0, 0);
      acc[1][0][fj] = __builtin_amdgcn_mfma_f32_16x16x32_f16(av1, bf0, acc[1][0][fj], 0, 0, 0);
      acc[0][1][fj] = __builtin_amdgcn_mfma_f32_16x16x32_f16(av0, bf1, acc[0][1][fj], 0, 0, 0);
      acc[1][1][fj] = __builtin_amdgcn_mfma_f32_16x16x32_f16(av1, bf1, acc[1][1][fj], 0, 0, 0);
    }
  }

  // ---- Merged softmax: wave-local max+sumexp, one cross-wave combine ---
  #pragma unroll
  for (int fi = 0; fi < 2; ++fi) {
    #pragma unroll
    for (int r = 0; r < 4; ++r) {
      int row = 16 * fi + 4 * g + r;
      float mx = -1e30f;
      #pragma unroll
      for (int jj = 0; jj < 2; ++jj)
        #pragma unroll
        for (int fj = 0; fj < 4; ++fj) {
          float v = acc[fi][jj][fj][r] + sqv_l[128 * w + 64 * jj + 16 * fj + l15];
          acc[fi][jj][fj][r] = v;
          mx = fmaxf(mx, v);
        }
      mx = fmaxf(mx, __shfl_xor(mx, 1, 64));
      mx = fmaxf(mx, __shfl_xor(mx, 2, 64));
      mx = fmaxf(mx, __shfl_xor(mx, 4, 64));
      mx = fmaxf(mx, __shfl_xor(mx, 8, 64));
      float s = 0.f;
      #pragma unroll
      for (int jj = 0; jj < 2; ++jj)
        #pragma unroll
        for (int fj = 0; fj < 4; ++fj) {
          float p = __expf(acc[fi][jj][fj][r] - mx);
          acc[fi][jj][fj][r] = p;
          s += p;
        }
      s += __shfl_xor(s, 1, 64); s += __shfl_xor(s, 2, 64);
      s += __shfl_xor(s, 4, 64); s += __shfl_xor(s, 8, 64);
      if (l15 == 0) { red_m[w][row] = mx; red_s[w][row] = s; }
    }
  }
  __syncthreads();
  if (tid < 32) {
    float m0 = red_m[0][tid], m1 = red_m[1][tid];
    float m2 = red_m[2][tid], m3 = red_m[3][tid];
    float m = fmaxf(fmaxf(m0, m1), fmaxf(m2, m3));
    float e0 = __expf(m0 - m), e1 = __expf(m1 - m);
    float e2 = __expf(m2 - m), e3 = __expf(m3 - m);
    float stot = red_s[0][tid] * e0 + red_s[1][tid] * e1
               + red_s[2][tid] * e2 + red_s[3][tid] * e3;
    float inv = 1.0f / stot;
    fac[0][tid] = e0 * inv; fac[1][tid] = e1 * inv;
    fac[2][tid] = e2 * inv; fac[3][tid] = e3 * inv;
    mrow[b * CL_ + i0 + tid] = m + scv_l[tid];
  }
  __syncthreads();   // fac ready; cw_t dead from here (P_b aliases)

  // ---- write normalized P into swizzled LDS tile -----------------------
  #pragma unroll
  for (int fi = 0; fi < 2; ++fi) {
    #pragma unroll
    for (int r = 0; r < 4; ++r) {
      int row = 16 * fi + 4 * g + r;
      float f = fac[w][row];
      #pragma unroll
      for (int jj = 0; jj < 2; ++jj)
        #pragma unroll
        for (int fj = 0; fj < 4; ++fj) {
          int col = 256 * w + 128 * jj + 32 * fj + 2 * l15;   // byte col
          *(f16*)(P_b + (((row << 10) + col) ^ ((row & 7) << 4)))
              = (f16)(acc[fi][jj][fj][r] * f);
        }
    }
  }
  __syncthreads();   // P visible to all waves

  // ---- Phase C: c2q = P @ qT; wave w owns d in [64w,64w+64) ------------
  f32x4 o[2][2][2];   // [fi][Wl][fd]
  #pragma unroll
  for (int fi = 0; fi < 2; ++fi)
    #pragma unroll
    for (int Wl = 0; Wl < 2; ++Wl)
      #pragma unroll
      for (int fd = 0; fd < 2; ++fd)
        o[fi][Wl][fd] = (f32x4){0.f,0.f,0.f,0.f};
  const f16* qT0 = qTF + ((size_t)(b * 8 + 2 * w)) * 16384;
  const f16* qT1 = qT0 + 16384;
  #pragma unroll
  for (int jt = 0; jt < 16; ++jt) {
    f16x8 pa0 = *(const f16x8*)(P_b + ((((l15     ) << 10) + 64 * jt + 16 * g) ^ (((l15     ) & 7) << 4)));
    f16x8 pa1 = *(const f16x8*)(P_b + ((((16 + l15) << 10) + 64 * jt + 16 * g) ^ (((16 + l15) & 7) << 4)));
    #pragma unroll
    for (int fd = 0; fd < 2; ++fd) {
      f16x8 qf0 = *(const f16x8*)(qT0 + (((size_t)jt * 2 + fd) * 64 + l) * 8);
      f16x8 qf1 = *(const f16x8*)(qT1 + (((size_t)jt * 2 + fd) * 64 + l) * 8);
      o[0][0][fd] = __builtin_amdgcn_mfma_f32_16x16x32_f16(pa0, qf0, o[0][0][fd], 0, 0, 0);
      o[1][0][fd] = __builtin_amdgcn_mfma_f32_16x16x32_f16(pa1, qf0, o[1][0][fd], 0, 0, 0);
      o[0][1][fd] = __builtin_amdgcn_mfma_f32_16x16x32_f16(pa0, qf1, o[0][1][fd], 0, 0, 0);
      o[1][1][fd] = __builtin_amdgcn_mfma_f32_16x16x32_f16(pa1, qf1, o[1][1][fd], 0, 0, 0);
    }
  }
  __syncthreads();   // all P reads done before c2q_l overwrites

  // ---- tail: o -> f16 LDS -> coalesced compact store -------------------
  #pragma unroll
  for (int fi = 0; fi < 2; ++fi)
    #pragma unroll
    for (int Wl = 0; Wl < 2; ++Wl)
      #pragma unroll
      for (int fd = 0; fd < 2; ++fd)
        #pragma unroll
        for (int r = 0; r < 4; ++r)
          c2q_l[16 * fi + 4 * g + r][64 * w + 32 * Wl + 16 * fd + l15]
              = (f16)o[fi][Wl][fd][r];
  __syncthreads();
  f16* dst = c2qh + ((size_t)(b * CL_ + i0)) * 256;
  #pragma unroll
  for (int s = 0; s < 4; ++s) {
    int idx = tid + 256 * s;                 // 32 rows x 32 f16x8
    int row = idx >> 5, col8 = (idx & 31) * 8;
    *(f16x8*)(dst + (size_t)row * 256 + col8) = *(const f16x8*)(&c2q_l[row][col8]);
  }
}

// ------- K2a: bvec[b,:] = softmax_i(mrow[b,:]) ---------------------------
__global__ __launch_bounds__(256) void k2a_bvec(const float* __restrict__ mrow,
                                                float* __restrict__ bvec) {
  __shared__ float red[256];
  int b = blockIdx.x, tid = threadIdx.x;
  f32x4 v = *(const f32x4*)(mrow + b * CL_ + tid * 4);
  float mx = fmaxf(fmaxf(v[0], v[1]), fmaxf(v[2], v[3]));
  red[tid] = mx;
  __syncthreads();
  for (int s = 128; s > 0; s >>= 1) {
    if (tid < s) red[tid] = fmaxf(red[tid], red[tid + s]);
    __syncthreads();
  }
  float gmx = red[0];
  __syncthreads();
  f32x4 e;
  e[0] = __expf(v[0] - gmx); e[1] = __expf(v[1] - gmx);
  e[2] = __expf(v[2] - gmx); e[3] = __expf(v[3] - gmx);
  red[tid] = e[0] + e[1] + e[2] + e[3];
  __syncthreads();
  for (int s = 128; s > 0; s >>= 1) {
    if (tid < s) red[tid] += red[tid + s];
    __syncthreads();
  }
  float inv = 1.0f / red[0];
  e[0] *= inv; e[1] *= inv; e[2] *= inv; e[3] *= inv;
  *(f32x4*)(bvec + b * CL_ + tid * 4) = e;
}

// ------- K2b: part[b,ch,:] = sum_{i in chunk} bvec[i] * c[i,:] -----------
__global__ __launch_bounds__(256) void k2b_part(const float* __restrict__ c,
                                                const float* __restrict__ bvec,
                                                float* __restrict__ part) {
  __shared__ f32x4 pl[4][64];
  int ch = blockIdx.x, b = blockIdx.y, tid = threadIdx.x;
  int ro = tid >> 6, dl = tid & 63;
  const float* cb = c + ((size_t)b * CL_ + ch * 128) * D_;
  const float* bv = bvec + b * CL_ + ch * 128;
  f32x4 acc = (f32x4){0.f, 0.f, 0.f, 0.f};
  for (int i = ro; i < 128; i += 4) {
    float wgt = bv[i];
    f32x4 v = *(const f32x4*)(cb + (size_t)i * D_ + dl * 4);
    acc[0] += wgt * v[0]; acc[1] += wgt * v[1];
    acc[2] += wgt * v[2]; acc[3] += wgt * v[3];
  }
  pl[ro][dl] = acc;
  __syncthreads();
  if (tid < 64) {
    f32x4 s = (pl[0][tid] + pl[1][tid]) + (pl[2][tid] + pl[3][tid]);
    *(f32x4*)(part + ((size_t)(b * 8 + ch)) * D_ + tid * 4) = s;
  }
}

// ------- K2c: q2c[b,:] = sum_ch part[b,ch,:] -----------------------------
__global__ __launch_bounds__(256) void k2c_red(const float* __restrict__ part,
                                               float* __restrict__ q2c) {
  int b = blockIdx.x, d = threadIdx.x;
  float s = 0.f;
  #pragma unroll
  for (int ch = 0; ch < 8; ++ch) s += part[((size_t)(b * 8 + ch)) * D_ + d];
  q2c[b * D_ + d] = s;
}

// ------- K4: assemble out[0:4D] = [c, c2q, c*c2q, c*q2c] — pure stream ---
__global__ __launch_bounds__(256) void k4_out(const float* __restrict__ c,
                                              const f16* __restrict__ c2qh,
                                              const float* __restrict__ q2c,
                                              float* __restrict__ out) {
  size_t idx = (size_t)blockIdx.x * 256 + threadIdx.x;   // B*CL*64 f32x4
  int b   = (int)(idx >> 16);
  int rem = (int)(idx & 65535);
  int i = rem >> 6, d4 = (rem & 63) * 4;
  size_t rowoff = (size_t)(b * CL_ + i);
  f32x4 cv = *(const f32x4*)(c + rowoff * D_ + d4);
  f16x4 gh = *(const f16x4*)(c2qh + rowoff * 256 + d4);
  f32x4 gv;
  gv[0] = (float)gh[0]; gv[1] = (float)gh[1];
  gv[2] = (float)gh[2]; gv[3] = (float)gh[3];
  f32x4 qv = *(const f32x4*)(q2c + b * D_ + d4);
  f32x4 p2, p3;
  p2[0] = cv[0]*gv[0]; p2[1] = cv[1]*gv[1]; p2[2] = cv[2]*gv[2]; p2[3] = cv[3]*gv[3];
  p3[0] = cv[0]*qv[0]; p3[1] = cv[1]*qv[1]; p3[2] = cv[2]*qv[2]; p3[3] = cv[3]*qv[3];
  float* ob = out + rowoff * (4 * D_) + d4;
  *(f32x4*)(ob)          = cv;
  *(f32x4*)(ob + D_)     = gv;
  *(f32x4*)(ob + 2 * D_) = p2;
  *(f32x4*)(ob + 3 * D_) = p3;
}

extern "C" void kernel_launch(void* const* d_in, const int* in_sizes, int n_in,
                              void* d_out, int out_size, void* d_ws, size_t ws_size,
                              hipStream_t stream) {
  const float* c    = (const float*)d_in[0];
  const float* q    = (const float*)d_in[1];
  const float* w_c  = (const float*)d_in[2];
  const float* w_q  = (const float*)d_in[4];
  const float* w_cq = (const float*)d_in[6];
  float* out = (float*)d_out;
  char* ws = (char*)d_ws;
  f16*   qF   = (f16*)ws;                       //  8,388,608 B
  f16*   qTF  = (f16*)(ws + 8388608);           //  8,388,608 B
  float* sqv  = (float*)(ws + 16777216);        //     65,536 B
  float* mrow = (float*)(ws + 16842752);        //    131,072 B
  float* bvec = (float*)(ws + 16973824);        //    131,072 B
  float* part = (float*)(ws + 17104896);        //    262,144 B
  float* q2c  = (float*)(ws + 17367040);        //     32,768 B
  f16*   c2qh = (f16*)(ws + 17399808);          // 16,777,216 B (tot 34,177,024)

  hipLaunchKernelGGL(k0_prep,  dim3(8, 32),  dim3(256), 0, stream,
                     q, w_q, qF, qTF, sqv);
  hipLaunchKernelGGL(k1_fused, dim3(1024),   dim3(256), 0, stream,
                     c, qF, qTF, sqv, w_c, w_cq, c2qh, mrow);
  hipLaunchKernelGGL(k2a_bvec, dim3(32),     dim3(256), 0, stream, mrow, bvec);
  hipLaunchKernelGGL(k2b_part, dim3(8, 32),  dim3(256), 0, stream, c, bvec, part);
  hipLaunchKernelGGL(k2c_red,  dim3(32),     dim3(256), 0, stream, part, q2c);
  hipLaunchKernelGGL(k4_out,   dim3(8192),   dim3(256), 0, stream,
                     c, c2qh, q2c, out);
}

// Round 20
// 89.251 us; speedup vs baseline: 1.1569x; 1.1569x over previous
//
#include <hip/hip_runtime.h>

#define B_  32
#define CL_ 1024
#define QL_ 512
#define D_  256

typedef _Float16 f16;
typedef __attribute__((ext_vector_type(2))) _Float16 f16x2;
typedef __attribute__((ext_vector_type(4))) _Float16 f16x4;
typedef __attribute__((ext_vector_type(8))) _Float16 f16x8;
typedef __attribute__((ext_vector_type(4))) float    f32x4;

// ------- K0: q -> fragment-ordered qF/qTF + sqv --------------------------
__global__ __launch_bounds__(256) void k0_prep(const float* __restrict__ q,
                                               const float* __restrict__ w_q,
                                               f16* __restrict__ qF,
                                               f16* __restrict__ qTF,
                                               float* __restrict__ sqv) {
  __shared__ f16 q_l[64][258];
  int b = blockIdx.y, J = blockIdx.x, j0 = J * 64, tid = threadIdx.x;
  int r = tid >> 2, seg = tid & 3;
  const float* qrow = q + ((size_t)(b * QL_ + j0 + r)) * D_ + seg * 64;
  float dot = 0.f;
  #pragma unroll
  for (int u = 0; u < 16; ++u) {
    f32x4 v  = *(const f32x4*)(qrow + 4 * u);
    f32x4 wv = *(const f32x4*)(w_q + seg * 64 + 4 * u);
    f16x4 h;
    h[0] = (f16)v[0]; h[1] = (f16)v[1]; h[2] = (f16)v[2]; h[3] = (f16)v[3];
    *(f16x4*)(&q_l[r][seg * 64 + 4 * u]) = h;
    dot += v[0]*wv[0] + v[1]*wv[1] + v[2]*wv[2] + v[3]*wv[3];
  }
  dot += __shfl_xor(dot, 1, 64);
  dot += __shfl_xor(dot, 2, 64);
  if (seg == 0) sqv[b * QL_ + j0 + r] = dot;
  __syncthreads();

  const int ww = tid >> 6, l = tid & 63, g = l >> 4, l15 = l & 15;
  f16* qFb = qF + ((size_t)(b * 8 + J)) * 16384;
  #pragma unroll
  for (int t = 0; t < 8; ++t) {
    int task = ww * 8 + t;            // (dk,fj)
    int dk = task >> 2, fj = task & 3;
    f16x8 v = *(const f16x8*)(&q_l[16 * fj + l15][dk * 32 + 8 * g]);
    *(f16x8*)(qFb + ((size_t)task * 64 + l) * 8) = v;
  }
  #pragma unroll
  for (int t = 0; t < 8; ++t) {
    int task = ww * 8 + t;            // (W,jtl,fd)
    int W = task >> 2, jtl = (task >> 1) & 1, fd = task & 1;
    f16x8 v;
    #pragma unroll
    for (int e = 0; e < 8; ++e)
      v[e] = q_l[32 * jtl + 8 * g + e][32 * W + 16 * fd + l15];
    *(f16x8*)(qTF + ((((size_t)(b * 8 + W) * 16 + (2 * J + jtl)) * 2 + fd) * 64 + l) * 8) = v;
  }
}

// ------- K1, BM=64, 2 blocks/CU (R18 champion) + merged 1-pass softmax ---
// Wave-local max/exp/sum in ONE sweep; single cross-wave combine produces
// fac[w][row] = exp(m_w - m) / stot, folded into P scale. 2 barriers saved.
__global__ __launch_bounds__(512, 4) void k1_fused(
    const float* __restrict__ c, const f16* __restrict__ qF,
    const f16* __restrict__ qTF, const float* __restrict__ sqv,
    const float* __restrict__ w_c, const float* __restrict__ w_cq,
    f16* __restrict__ c2qh, float* __restrict__ mrow)
{
  __shared__ alignas(16) char smem[76032];
  f16 (*cw_t)[264]  = (f16 (*)[264])(smem);          // 33792 (phase A)
  char* P_b         = smem;                          // 65536 swz (B/C)
  f16 (*c2q_l)[264] = (f16 (*)[264])(smem);          // 33792 alias (tail)
  float* sqv_l = (float*)(smem + 65536);             // 2048
  float* wcq_l = (float*)(smem + 67584);             // 1024
  float* wc_l  = (float*)(smem + 68608);             // 1024
  float* scv_l = (float*)(smem + 69632);             // 256
  float (*red_m)[64] = (float (*)[64])(smem + 69888); // 2048
  float (*red_s)[64] = (float (*)[64])(smem + 71936); // 2048
  float (*fac)[64]   = (float (*)[64])(smem + 73984); // 2048

  const int tid = threadIdx.x;
  const int w = tid >> 6, l = tid & 63, g = l >> 4, l15 = l & 15;
  const int lin = blockIdx.x, xcd = lin & 7, slot = lin >> 3;   // 0..63
  const int b  = xcd * 4 + (slot >> 4);
  const int i0 = (slot & 15) * 64;

  if (tid < 256) { wcq_l[tid] = w_cq[tid]; wc_l[tid] = w_c[tid]; }
  sqv_l[tid] = sqv[b * QL_ + tid];
  __syncthreads();

  // ---- stage cw_t = f16(c * w_cq) (64 rows); scv = c . w_c -------------
  {
    int row = tid >> 3, seg = tid & 7;               // 8 thr/row, 32 f32 each
    const float* crow = c + (size_t)(b * CL_ + i0 + row) * D_ + seg * 32;
    float dot = 0.f;
    #pragma unroll
    for (int u = 0; u < 8; ++u) {
      f32x4 v  = *(const f32x4*)(crow + 4 * u);
      f32x4 wv = *(const f32x4*)(wcq_l + seg * 32 + 4 * u);
      f32x4 w2 = *(const f32x4*)(wc_l  + seg * 32 + 4 * u);
      f16x4 h;
      h[0] = (f16)(v[0]*wv[0]); h[1] = (f16)(v[1]*wv[1]);
      h[2] = (f16)(v[2]*wv[2]); h[3] = (f16)(v[3]*wv[3]);
      *(f16x4*)(&cw_t[row][seg * 32 + 4 * u]) = h;
      dot += v[0]*w2[0] + v[1]*w2[1] + v[2]*w2[2] + v[3]*w2[3];
    }
    dot += __shfl_xor(dot, 1, 64); dot += __shfl_xor(dot, 2, 64);
    dot += __shfl_xor(dot, 4, 64);
    if (seg == 0) scv_l[row] = dot;
  }
  __syncthreads();

  // ---- Phase A: fragment streams; wave w owns j in [64w,64w+64) --------
  f32x4 acc[4][4];
  #pragma unroll
  for (int fi = 0; fi < 4; ++fi)
    #pragma unroll
    for (int fj = 0; fj < 4; ++fj)
      acc[fi][fj] = (f32x4){0.f,0.f,0.f,0.f};

  const f16* qFb = qF + ((size_t)(b * 8 + w)) * 16384;
  #pragma unroll
  for (int dk = 0; dk < 8; ++dk) {
    f16x8 av[4];
    #pragma unroll
    for (int fi = 0; fi < 4; ++fi)
      av[fi] = *(const f16x8*)(&cw_t[16 * fi + l15][dk * 32 + 8 * g]);
    #pragma unroll
    for (int fj = 0; fj < 4; ++fj) {
      f16x8 bf = *(const f16x8*)(qFb + (((size_t)dk * 4 + fj) * 64 + l) * 8);
      #pragma unroll
      for (int fi = 0; fi < 4; ++fi)
        acc[fi][fj] = __builtin_amdgcn_mfma_f32_16x16x32_f16(av[fi], bf, acc[fi][fj], 0, 0, 0);
    }
  }

  // ---- Merged 1-pass softmax: local max+exp+sum, one combine -----------
  #pragma unroll
  for (int fi = 0; fi < 4; ++fi) {
    #pragma unroll
    for (int r = 0; r < 4; ++r) {
      int row = 16 * fi + 4 * g + r;
      float mx = -1e30f;
      #pragma unroll
      for (int fj = 0; fj < 4; ++fj) {
        float v = acc[fi][fj][r] + sqv_l[64 * w + 16 * fj + l15];
        acc[fi][fj][r] = v;
        mx = fmaxf(mx, v);
      }
      mx = fmaxf(mx, __shfl_xor(mx, 1, 64));
      mx = fmaxf(mx, __shfl_xor(mx, 2, 64));
      mx = fmaxf(mx, __shfl_xor(mx, 4, 64));
      mx = fmaxf(mx, __shfl_xor(mx, 8, 64));
      float s = 0.f;
      #pragma unroll
      for (int fj = 0; fj < 4; ++fj) {
        float p = __expf(acc[fi][fj][r] - mx);
        acc[fi][fj][r] = p;
        s += p;
      }
      s += __shfl_xor(s, 1, 64); s += __shfl_xor(s, 2, 64);
      s += __shfl_xor(s, 4, 64); s += __shfl_xor(s, 8, 64);
      if (l15 == 0) { red_m[w][row] = mx; red_s[w][row] = s; }
    }
  }
  __syncthreads();
  if (tid < 64) {
    float m = red_m[0][tid];
    #pragma unroll
    for (int w2 = 1; w2 < 8; ++w2) m = fmaxf(m, red_m[w2][tid]);
    float stot = 0.f;
    float e[8];
    #pragma unroll
    for (int w2 = 0; w2 < 8; ++w2) {
      e[w2] = __expf(red_m[w2][tid] - m);
      stot += red_s[w2][tid] * e[w2];
    }
    float inv = 1.0f / stot;
    #pragma unroll
    for (int w2 = 0; w2 < 8; ++w2) fac[w2][tid] = e[w2] * inv;
    mrow[b * CL_ + i0 + tid] = m + scv_l[tid];
  }
  __syncthreads();   // fac ready; cw_t dead (P_b aliases)

  // ---- write normalized P into swizzled LDS tile -----------------------
  #pragma unroll
  for (int fi = 0; fi < 4; ++fi) {
    #pragma unroll
    for (int r = 0; r < 4; ++r) {
      int row = 16 * fi + 4 * g + r;
      float f = fac[w][row];
      #pragma unroll
      for (int fj = 0; fj < 4; ++fj) {
        *(f16*)(P_b + (((row << 10) + 128 * w + 32 * fj + 2 * l15) ^ ((row & 7) << 4)))
            = (f16)(acc[fi][fj][r] * f);
      }
    }
  }
  __syncthreads();   // P visible to all waves

  // ---- Phase C: c2q = P @ qT; wave w owns d in [32w,32w+32) ------------
  f32x4 o[4][2];
  #pragma unroll
  for (int fi = 0; fi < 4; ++fi) { o[fi][0] = (f32x4){0.f,0.f,0.f,0.f}; o[fi][1] = o[fi][0]; }
  const f16* qTFb = qTF + ((size_t)(b * 8 + w)) * 16384;
  #pragma unroll
  for (int jt = 0; jt < 16; ++jt) {
    f16x8 qf0 = *(const f16x8*)(qTFb + (((size_t)jt * 2 + 0) * 64 + l) * 8);
    f16x8 qf1 = *(const f16x8*)(qTFb + (((size_t)jt * 2 + 1) * 64 + l) * 8);
    #pragma unroll
    for (int fi = 0; fi < 4; ++fi) {
      int row = 16 * fi + l15;
      f16x8 pa = *(const f16x8*)(P_b + (((row << 10) + 64 * jt + 16 * g) ^ ((row & 7) << 4)));
      o[fi][0] = __builtin_amdgcn_mfma_f32_16x16x32_f16(pa, qf0, o[fi][0], 0, 0, 0);
      o[fi][1] = __builtin_amdgcn_mfma_f32_16x16x32_f16(pa, qf1, o[fi][1], 0, 0, 0);
    }
  }
  __syncthreads();   // all P reads done before c2q_l overwrites

  // ---- tail: o -> f16 LDS -> coalesced compact store -------------------
  #pragma unroll
  for (int fi = 0; fi < 4; ++fi)
    #pragma unroll
    for (int fd = 0; fd < 2; ++fd)
      #pragma unroll
      for (int r = 0; r < 4; ++r)
        c2q_l[16 * fi + 4 * g + r][32 * w + 16 * fd + l15] = (f16)o[fi][fd][r];
  __syncthreads();
  f16* dst = c2qh + ((size_t)(b * CL_ + i0)) * 256;
  #pragma unroll
  for (int s = 0; s < 4; ++s) {
    int idx = tid + 512 * s;                 // 64 rows x 32 f16x8
    int row = idx >> 5, col8 = (idx & 31) * 8;
    *(f16x8*)(dst + (size_t)row * 256 + col8) = *(const f16x8*)(&c2q_l[row][col8]);
  }
}

// ------- K2a: bvec[b,:] = softmax_i(mrow[b,:]) ---------------------------
__global__ __launch_bounds__(256) void k2a_bvec(const float* __restrict__ mrow,
                                                float* __restrict__ bvec) {
  __shared__ float red[256];
  int b = blockIdx.x, tid = threadIdx.x;
  f32x4 v = *(const f32x4*)(mrow + b * CL_ + tid * 4);
  float mx = fmaxf(fmaxf(v[0], v[1]), fmaxf(v[2], v[3]));
  red[tid] = mx;
  __syncthreads();
  for (int s = 128; s > 0; s >>= 1) {
    if (tid < s) red[tid] = fmaxf(red[tid], red[tid + s]);
    __syncthreads();
  }
  float gmx = red[0];
  __syncthreads();
  f32x4 e;
  e[0] = __expf(v[0] - gmx); e[1] = __expf(v[1] - gmx);
  e[2] = __expf(v[2] - gmx); e[3] = __expf(v[3] - gmx);
  red[tid] = e[0] + e[1] + e[2] + e[3];
  __syncthreads();
  for (int s = 128; s > 0; s >>= 1) {
    if (tid < s) red[tid] += red[tid + s];
    __syncthreads();
  }
  float inv = 1.0f / red[0];
  e[0] *= inv; e[1] *= inv; e[2] *= inv; e[3] *= inv;
  *(f32x4*)(bvec + b * CL_ + tid * 4) = e;
}

// ------- K2b: part[b,ch,:] = sum_{i in chunk} bvec[i] * c[i,:] -----------
__global__ __launch_bounds__(256) void k2b_part(const float* __restrict__ c,
                                                const float* __restrict__ bvec,
                                                float* __restrict__ part) {
  __shared__ f32x4 pl[4][64];
  int ch = blockIdx.x, b = blockIdx.y, tid = threadIdx.x;
  int ro = tid >> 6, dl = tid & 63;
  const float* cb = c + ((size_t)b * CL_ + ch * 128) * D_;
  const float* bv = bvec + b * CL_ + ch * 128;
  f32x4 acc = (f32x4){0.f, 0.f, 0.f, 0.f};
  for (int i = ro; i < 128; i += 4) {
    float wgt = bv[i];
    f32x4 v = *(const f32x4*)(cb + (size_t)i * D_ + dl * 4);
    acc[0] += wgt * v[0]; acc[1] += wgt * v[1];
    acc[2] += wgt * v[2]; acc[3] += wgt * v[3];
  }
  pl[ro][dl] = acc;
  __syncthreads();
  if (tid < 64) {
    f32x4 s = (pl[0][tid] + pl[1][tid]) + (pl[2][tid] + pl[3][tid]);
    *(f32x4*)(part + ((size_t)(b * 8 + ch)) * D_ + tid * 4) = s;
  }
}

// ------- K2c: q2c[b,:] = sum_ch part[b,ch,:] -----------------------------
__global__ __launch_bounds__(256) void k2c_red(const float* __restrict__ part,
                                               float* __restrict__ q2c) {
  int b = blockIdx.x, d = threadIdx.x;
  float s = 0.f;
  #pragma unroll
  for (int ch = 0; ch < 8; ++ch) s += part[((size_t)(b * 8 + ch)) * D_ + d];
  q2c[b * D_ + d] = s;
}

// ------- K4: assemble out[0:4D] = [c, c2q, c*c2q, c*q2c] — pure stream ---
__global__ __launch_bounds__(256) void k4_out(const float* __restrict__ c,
                                              const f16* __restrict__ c2qh,
                                              const float* __restrict__ q2c,
                                              float* __restrict__ out) {
  size_t idx = (size_t)blockIdx.x * 256 + threadIdx.x;   // B*CL*64 f32x4
  int b   = (int)(idx >> 16);
  int rem = (int)(idx & 65535);
  int i = rem >> 6, d4 = (rem & 63) * 4;
  size_t rowoff = (size_t)(b * CL_ + i);
  f32x4 cv = *(const f32x4*)(c + rowoff * D_ + d4);
  f16x4 gh = *(const f16x4*)(c2qh + rowoff * 256 + d4);
  f32x4 gv;
  gv[0] = (float)gh[0]; gv[1] = (float)gh[1];
  gv[2] = (float)gh[2]; gv[3] = (float)gh[3];
  f32x4 qv = *(const f32x4*)(q2c + b * D_ + d4);
  f32x4 p2, p3;
  p2[0] = cv[0]*gv[0]; p2[1] = cv[1]*gv[1]; p2[2] = cv[2]*gv[2]; p2[3] = cv[3]*gv[3];
  p3[0] = cv[0]*qv[0]; p3[1] = cv[1]*qv[1]; p3[2] = cv[2]*qv[2]; p3[3] = cv[3]*qv[3];
  float* ob = out + rowoff * (4 * D_) + d4;
  *(f32x4*)(ob)          = cv;
  *(f32x4*)(ob + D_)     = gv;
  *(f32x4*)(ob + 2 * D_) = p2;
  *(f32x4*)(ob + 3 * D_) = p3;
}

extern "C" void kernel_launch(void* const* d_in, const int* in_sizes, int n_in,
                              void* d_out, int out_size, void* d_ws, size_t ws_size,
                              hipStream_t stream) {
  const float* c    = (const float*)d_in[0];
  const float* q    = (const float*)d_in[1];
  const float* w_c  = (const float*)d_in[2];
  const float* w_q  = (const float*)d_in[4];
  const float* w_cq = (const float*)d_in[6];
  float* out = (float*)d_out;
  char* ws = (char*)d_ws;
  f16*   qF   = (f16*)ws;                       //  8,388,608 B
  f16*   qTF  = (f16*)(ws + 8388608);           //  8,388,608 B
  float* sqv  = (float*)(ws + 16777216);        //     65,536 B
  float* mrow = (float*)(ws + 16842752);        //    131,072 B
  float* bvec = (float*)(ws + 16973824);        //    131,072 B
  float* part = (float*)(ws + 17104896);        //    262,144 B
  float* q2c  = (float*)(ws + 17367040);        //     32,768 B
  f16*   c2qh = (f16*)(ws + 17399808);          // 16,777,216 B (tot 34,177,024)

  hipLaunchKernelGGL(k0_prep,  dim3(8, 32),  dim3(256), 0, stream,
                     q, w_q, qF, qTF, sqv);
  hipLaunchKernelGGL(k1_fused, dim3(512),    dim3(512), 0, stream,
                     c, qF, qTF, sqv, w_c, w_cq, c2qh, mrow);
  hipLaunchKernelGGL(k2a_bvec, dim3(32),     dim3(256), 0, stream, mrow, bvec);
  hipLaunchKernelGGL(k2b_part, dim3(8, 32),  dim3(256), 0, stream, c, bvec, part);
  hipLaunchKernelGGL(k2c_red,  dim3(32),     dim3(256), 0, stream, part, q2c);
  hipLaunchKernelGGL(k4_out,   dim3(8192),   dim3(256), 0, stream,
                     c, c2qh, q2c, out);
}